// Round 1
// baseline (77.384 us; speedup 1.0000x reference)
//
#include <hip/hip_runtime.h>

// HardTripletMiningLoss: 480 embeddings (anchor|positive|negative), D=128.
// Reference: td[i,j,k] = pd[i,j] - pd[j,k] + A, keep = same[i,j] & !same[j,k],
// keep[0,:,:] = False.  j is the anchor; pd symmetric => per anchor row a:
//   positives i: label[i]==label[a] && i != 0
//   negatives k: label[k]!=label[a]
//   sum/count of relu(pd[a,i] + A - pd[a,k])

#define NROWS 480
#define DDIM  128
#define BLK   256
#define MARGIN 0.2f

__device__ __forceinline__ const float* emb_row(const float* a, const float* p,
                                                const float* n, int r) {
  if (r < 160) return a + r * DDIM;
  if (r < 320) return p + (r - 160) * DDIM;
  return n + (r - 320) * DDIM;
}

__global__ __launch_bounds__(BLK) void triplet_rows(
    const float* __restrict__ anch, const float* __restrict__ posi,
    const float* __restrict__ nega, const int* __restrict__ ind,
    float* __restrict__ partials) {
  __shared__ float ei[DDIM];
  __shared__ float pdrow[NROWS];
  __shared__ int   labels[NROWS];
  __shared__ int   poslist[NROWS];
  __shared__ int   npos;
  __shared__ float red_s[BLK / 64], red_c[BLK / 64];

  const int tid = threadIdx.x;
  const int a = blockIdx.x;  // anchor row (j in reference notation)

  for (int t = tid; t < NROWS; t += BLK) labels[t] = ind[t];
  if (tid == 0) npos = 0;
  {
    const float* ra = emb_row(anch, posi, nega, a);
    if (tid < DDIM) ei[tid] = ra[tid];
  }
  __syncthreads();

  const int la = labels[a];
  for (int r = tid; r < NROWS; r += BLK) {
    const float4* er = (const float4*)emb_row(anch, posi, nega, r);
    float d2 = 0.f;
#pragma unroll
    for (int dd = 0; dd < DDIM / 4; ++dd) {
      float4 b = er[dd];
      float x0 = ei[4 * dd + 0] - b.x;
      float x1 = ei[4 * dd + 1] - b.y;
      float x2 = ei[4 * dd + 2] - b.z;
      float x3 = ei[4 * dd + 3] - b.w;
      d2 += x0 * x0 + x1 * x1 + x2 * x2 + x3 * x3;
    }
    pdrow[r] = d2;  // exact ||e_a - e_r||^2, symmetric, >= 0
    if (labels[r] == la && r != 0) {  // positive list; i==0 slice excluded
      int slot = atomicAdd(&npos, 1);
      poslist[slot] = r;
    }
  }
  __syncthreads();

  float s = 0.f, c = 0.f;
  {
    // each thread owns k = tid and k = tid+256 (tail guarded)
    const int k0 = tid, k1 = tid + BLK;
    const float pk0 = pdrow[k0];
    const bool g0 = (labels[k0] != la);
    float pk1 = 0.f;
    bool g1 = false;
    if (k1 < NROWS) { pk1 = pdrow[k1]; g1 = (labels[k1] != la); }
    const int np = npos;
    for (int ii = 0; ii < np; ++ii) {
      const float tb = pdrow[poslist[ii]] + MARGIN;
      float td0 = tb - pk0;
      if (g0 && td0 > 0.f) { s += td0; c += 1.f; }
      float td1 = tb - pk1;
      if (g1 && td1 > 0.f) { s += td1; c += 1.f; }
    }
  }

  // block reduction: wave64 shuffle then cross-wave via LDS
  for (int off = 32; off > 0; off >>= 1) {
    s += __shfl_down(s, off, 64);
    c += __shfl_down(c, off, 64);
  }
  const int wave = tid >> 6, lane = tid & 63;
  if (lane == 0) { red_s[wave] = s; red_c[wave] = c; }
  __syncthreads();
  if (tid == 0) {
    float ts = 0.f, tc = 0.f;
    for (int w = 0; w < BLK / 64; ++w) { ts += red_s[w]; tc += red_c[w]; }
    partials[2 * a] = ts;
    partials[2 * a + 1] = tc;
  }
}

__global__ void triplet_finalize(const float* __restrict__ partials,
                                 float* __restrict__ out) {
  const int t = threadIdx.x;  // 64 threads, one wave
  double s = 0.0, c = 0.0;
  for (int b = t; b < NROWS; b += 64) {
    s += (double)partials[2 * b];
    c += (double)partials[2 * b + 1];
  }
  for (int off = 32; off > 0; off >>= 1) {
    s += __shfl_down(s, off, 64);
    c += __shfl_down(c, off, 64);
  }
  if (t == 0) out[0] = (c > 0.0) ? (float)(s / c) : 0.0f;
}

extern "C" void kernel_launch(void* const* d_in, const int* in_sizes, int n_in,
                              void* d_out, int out_size, void* d_ws, size_t ws_size,
                              hipStream_t stream) {
  const float* anch = (const float*)d_in[0];
  const float* posi = (const float*)d_in[1];
  const float* nega = (const float*)d_in[2];
  const int*   ind  = (const int*)d_in[3];
  float* out = (float*)d_out;
  float* partials = (float*)d_ws;  // 480 * 2 floats = 3.84 KB

  triplet_rows<<<NROWS, BLK, 0, stream>>>(anch, posi, nega, ind, partials);
  triplet_finalize<<<1, 64, 0, stream>>>(partials, out);
}